// Round 1
// baseline (57451.550 us; speedup 1.0000x reference)
//
#include <hip/hip_runtime.h>
#include <cstdint>

#define A_N 50000
#define E_N 1200000
#define T_N 2000000
#define G_N 500
#define U_N 64
#define RBF_N 48
#define NB 3

__device__ __forceinline__ float sigf(float x){ return 1.0f/(1.0f+__expf(-x)); }
__device__ __forceinline__ float siluf(float x){ return x/(1.0f+__expf(-x)); }

// atom = emb[atom_types]   (A x 64)
__global__ void k_atom_init(const int* __restrict__ types, const float* __restrict__ emb,
                            float* __restrict__ atom){
  int idx = blockIdx.x*256 + threadIdx.x;   // over A*64, exact
  int a = idx >> 6, u = idx & 63;
  atom[idx] = emb[types[a]*U_N + u];
}

// bond = silu(rbf @ bW + bb)   (E x 64)
__global__ void k_bond_init(const float* __restrict__ rbf, const float* __restrict__ bW,
                            const float* __restrict__ bb, float* __restrict__ bond){
  int idx = blockIdx.x*256 + threadIdx.x;   // over E*64, exact
  int e = idx >> 6, u = idx & 63;
  float acc = bb[u];
  acc += rbf[e*3+0]*bW[0*U_N+u];
  acc += rbf[e*3+1]*bW[1*U_N+u];
  acc += rbf[e*3+2]*bW[2*U_N+u];
  bond[idx] = siluf(acc);
}

// end_atom[t] = dst[tb1[t]]
__global__ void k_end(const int* __restrict__ tbi, const int* __restrict__ bai,
                      int* __restrict__ end_atom){
  int t = blockIdx.x*256 + threadIdx.x;
  if (t < T_N) end_atom[t] = bai[2*tbi[2*t+1]+1];
}

// tuo = sigmoid(atom @ tuW + tub)   (A x 48)
__global__ void k_tu(const float* __restrict__ atom, const float* __restrict__ tuW,
                     const float* __restrict__ tub, float* __restrict__ tuo){
  int idx = blockIdx.x*256 + threadIdx.x;   // over A*48, exact
  int a = idx / 48, r = idx - a*48;
  const float* ar = atom + a*U_N;
  float acc = tub[r];
  #pragma unroll
  for (int v=0; v<U_N; ++v) acc += ar[v]*tuW[v*48+r];
  tuo[idx] = sigf(acc);
}

// agg[tb0] += three_basis * tuo[end_atom]
__global__ void k_triple(const float* __restrict__ tb, const int* __restrict__ tbi,
                         const int* __restrict__ end_atom, const float* __restrict__ tuo,
                         float* __restrict__ agg){
  int idx = blockIdx.x*256 + threadIdx.x;   // over T*48, exact
  int t = idx / 48, r = idx - t*48;
  int b0 = tbi[2*t];
  float w = tuo[end_atom[t]*48 + r];
  atomicAdd(&agg[b0*48 + r], tb[idx]*w);
}

// Fused per-edge: bond += tf(agg); bond += gb(cat); msg = ga(bond); atom_next += msg
// One wave (64 threads) per block; each lane owns one edge. Weight indices are
// wave-uniform -> scalar loads; per-lane data lives in VGPRs; bond rows round-trip
// through one padded LDS buffer (stride 65) for coalesced global I/O.
__global__ __launch_bounds__(64) void k_edge(
    const float* __restrict__ agg, float* __restrict__ bond,
    const float* __restrict__ atomc, float* __restrict__ atomn,
    const int* __restrict__ bai,
    const float* __restrict__ tfW1, const float* __restrict__ tfb1,
    const float* __restrict__ tfW2, const float* __restrict__ tfb2,
    const float* __restrict__ gbW1, const float* __restrict__ gbb1,
    const float* __restrict__ gbW2, const float* __restrict__ gbb2,
    const float* __restrict__ gaW1, const float* __restrict__ gab1,
    const float* __restrict__ gaW2, const float* __restrict__ gab2)
{
  __shared__ float s_b[64*65];
  const int lane  = threadIdx.x;
  const int ebase = blockIdx.x*64;
  const int e     = ebase + lane;

  // coalesced load: bond rows for this wave's 64 edges
  #pragma unroll 1
  for (int i=0;i<64;++i) s_b[i*65+lane] = bond[(ebase+i)*64 + lane];

  // ---- phase 1: tf ----
  {
    float a[48];
    const float4* ap = (const float4*)(agg + (size_t)e*48);
    #pragma unroll
    for (int r=0;r<12;++r){ float4 v = ap[r]; a[4*r]=v.x; a[4*r+1]=v.y; a[4*r+2]=v.z; a[4*r+3]=v.w; }
    #pragma unroll 2
    for (int u=0;u<64;++u){
      float a1 = tfb1[u], a2 = tfb2[u];
      float p1 = 0.f, p2 = 0.f;
      #pragma unroll
      for (int k=0;k<24;++k){ a1 += a[k]*tfW1[k*64+u]; a2 += a[k]*tfW2[k*64+u]; }
      #pragma unroll
      for (int k=24;k<48;++k){ p1 += a[k]*tfW1[k*64+u]; p2 += a[k]*tfW2[k*64+u]; }
      a1 += p1; a2 += p2;
      s_b[lane*65+u] += siluf(a1)*sigf(a2);
    }
  }

  // ---- phase 2: gb (cat = [atom[src], atom[dst], bond_new]) ----
  const int src = bai[2*e], dst = bai[2*e+1];
  {
    float cat[192];
    const float4* sp = (const float4*)(atomc + (size_t)src*64);
    const float4* dp = (const float4*)(atomc + (size_t)dst*64);
    #pragma unroll
    for (int r=0;r<16;++r){ float4 v=sp[r]; cat[4*r]=v.x; cat[4*r+1]=v.y; cat[4*r+2]=v.z; cat[4*r+3]=v.w; }
    #pragma unroll
    for (int r=0;r<16;++r){ float4 v=dp[r]; cat[64+4*r]=v.x; cat[64+4*r+1]=v.y; cat[64+4*r+2]=v.z; cat[64+4*r+3]=v.w; }
    #pragma unroll
    for (int k=0;k<64;++k) cat[128+k] = s_b[lane*65+k];
    // s_b now free -> reuse it for the final bond value
    #pragma unroll 2
    for (int u=0;u<64;++u){
      float a1 = gbb1[u], a2 = gbb2[u];
      float p1=0.f,p2=0.f;
      #pragma unroll
      for (int k=0;k<96;++k){ a1 += cat[k]*gbW1[k*64+u]; a2 += cat[k]*gbW2[k*64+u]; }
      #pragma unroll
      for (int k=96;k<192;++k){ p1 += cat[k]*gbW1[k*64+u]; p2 += cat[k]*gbW2[k*64+u]; }
      a1 += p1; a2 += p2;
      s_b[lane*65+u] = cat[128+u] + siluf(a1)*sigf(a2);
    }
  }

  // ---- phase 3: ga -> msg -> atomic accumulate into atom_next ----
  {
    float f[64];
    #pragma unroll
    for (int k=0;k<64;++k) f[k] = s_b[lane*65+k];
    #pragma unroll 2
    for (int u=0;u<64;++u){
      float a1 = gab1[u], a2 = gab2[u];
      float p1=0.f,p2=0.f;
      #pragma unroll
      for (int k=0;k<32;++k){ a1 += f[k]*gaW1[k*64+u]; a2 += f[k]*gaW2[k*64+u]; }
      #pragma unroll
      for (int k=32;k<64;++k){ p1 += f[k]*gaW1[k*64+u]; p2 += f[k]*gaW2[k*64+u]; }
      a1 += p1; a2 += p2;
      float msg = siluf(a1)*sigf(a2);
      atomicAdd(&atomn[(size_t)dst*64+u], msg);
    }
  }

  // coalesced store of final bond
  #pragma unroll 1
  for (int i=0;i<64;++i) bond[(ebase+i)*64 + lane] = s_b[i*65+lane];
}

// gate = sig(atom @ wrW + wrb); num[b] += gate*atom; cnt[b] += 1
__global__ void k_gate(const float* __restrict__ atom, const int* __restrict__ batch,
                       const float* __restrict__ wrW, const float* __restrict__ wrb,
                       float* __restrict__ num, float* __restrict__ cnt){
  int idx = blockIdx.x*256 + threadIdx.x;   // over A*64, exact
  int a = idx >> 6, u = idx & 63;
  const float* ar = atom + (size_t)a*64;
  float acc = wrb[u];
  #pragma unroll
  for (int v=0;v<64;++v) acc += ar[v]*wrW[v*64+u];
  float g = sigf(acc);
  int b = batch[a];
  atomicAdd(&num[b*64+u], g*ar[u]);
  if (u==0) atomicAdd(&cnt[b], 1.0f);
}

// out[g] = silu(vec @ fW1 + fb1) @ fW2 + fb2,  vec = num/max(cnt,1)
__global__ __launch_bounds__(64) void k_final(const float* __restrict__ num, const float* __restrict__ cnt,
                        const float* __restrict__ fW1, const float* __restrict__ fb1,
                        const float* __restrict__ fW2, const float* __restrict__ fb2,
                        float* __restrict__ out){
  int g = blockIdx.x; int u = threadIdx.x;
  float inv = 1.0f / fmaxf(cnt[g], 1.0f);
  float acc = fb1[u];
  #pragma unroll
  for (int v=0;v<64;++v) acc += num[g*64+v]*inv*fW1[v*64+u];
  float p = siluf(acc)*fW2[u];
  #pragma unroll
  for (int off=32; off>0; off>>=1) p += __shfl_down(p, off, 64);
  if (u==0) out[g] = p + fb2[0];
}

extern "C" void kernel_launch(void* const* d_in, const int* in_sizes, int n_in,
                              void* d_out, int out_size, void* d_ws, size_t ws_size,
                              hipStream_t stream){
  const int*   atom_types = (const int*)d_in[0];
  const int*   bai   = (const int*)d_in[1];
  const int*   tbi   = (const int*)d_in[2];
  const int*   batch = (const int*)d_in[3];
  const float* rbf   = (const float*)d_in[4];
  const float* tb    = (const float*)d_in[5];
  const float* emb   = (const float*)d_in[6];
  const float* bW    = (const float*)d_in[7];
  const float* bb    = (const float*)d_in[8];
  const float* tuW   = (const float*)d_in[9];
  const float* tub   = (const float*)d_in[10];
  const float* tfW1  = (const float*)d_in[11];
  const float* tfb1  = (const float*)d_in[12];
  const float* tfW2  = (const float*)d_in[13];
  const float* tfb2  = (const float*)d_in[14];
  const float* gbW1  = (const float*)d_in[15];
  const float* gbb1  = (const float*)d_in[16];
  const float* gbW2  = (const float*)d_in[17];
  const float* gbb2  = (const float*)d_in[18];
  const float* gaW1  = (const float*)d_in[19];
  const float* gab1  = (const float*)d_in[20];
  const float* gaW2  = (const float*)d_in[21];
  const float* gab2  = (const float*)d_in[22];
  const float* wrW   = (const float*)d_in[23];
  const float* wrb   = (const float*)d_in[24];
  const float* fW1   = (const float*)d_in[25];
  const float* fb1   = (const float*)d_in[26];
  const float* fW2   = (const float*)d_in[27];
  const float* fb2   = (const float*)d_in[28];

  char* ws = (char*)d_ws;
  size_t off = 0;
  auto alloc = [&](size_t bytes)->char* {
    char* p = ws + off; off += (bytes + 255) & ~size_t(255); return p;
  };
  float* bond    = (float*)alloc((size_t)E_N*64*4);   // 307.2 MB
  float* agg     = (float*)alloc((size_t)E_N*48*4);   // 230.4 MB
  float* atomA   = (float*)alloc((size_t)A_N*64*4);   // 12.8 MB
  float* atomB   = (float*)alloc((size_t)A_N*64*4);   // 12.8 MB
  float* tuo     = (float*)alloc((size_t)A_N*48*4);   // 9.6 MB
  int*   end_atom= (int*)  alloc((size_t)T_N*4);      // 8 MB
  float* num     = (float*)alloc((size_t)G_N*64*4);
  float* cnt     = (float*)alloc((size_t)G_N*4);

  k_atom_init<<<A_N*64/256, 256, 0, stream>>>(atom_types, emb, atomA);
  k_bond_init<<<E_N*64/256, 256, 0, stream>>>(rbf, bW, bb, bond);
  k_end<<<(T_N+255)/256, 256, 0, stream>>>(tbi, bai, end_atom);
  hipMemsetAsync(num, 0, G_N*64*4, stream);
  hipMemsetAsync(cnt, 0, G_N*4, stream);

  float* cur = atomA; float* nxt = atomB;
  for (int i=0;i<NB;++i){
    k_tu<<<A_N*48/256, 256, 0, stream>>>(cur, tuW + (size_t)i*64*48, tub + (size_t)i*48, tuo);
    hipMemsetAsync(agg, 0, (size_t)E_N*48*4, stream);
    k_triple<<<T_N*48/256, 256, 0, stream>>>(tb, tbi, end_atom, tuo, agg);
    hipMemcpyAsync(nxt, cur, (size_t)A_N*64*4, hipMemcpyDeviceToDevice, stream);
    k_edge<<<E_N/64, 64, 0, stream>>>(agg, bond, cur, nxt, bai,
        tfW1 + (size_t)i*48*64, tfb1 + (size_t)i*64,
        tfW2 + (size_t)i*48*64, tfb2 + (size_t)i*64,
        gbW1 + (size_t)i*192*64, gbb1 + (size_t)i*64,
        gbW2 + (size_t)i*192*64, gbb2 + (size_t)i*64,
        gaW1 + (size_t)i*64*64, gab1 + (size_t)i*64,
        gaW2 + (size_t)i*64*64, gab2 + (size_t)i*64);
    float* t2 = cur; cur = nxt; nxt = t2;
  }
  k_gate<<<A_N*64/256, 256, 0, stream>>>(cur, batch, wrW, wrb, num, cnt);
  k_final<<<G_N, 64, 0, stream>>>(num, cnt, fW1, fb1, fW2, fb2, (float*)d_out);
}

// Round 2
// 16622.594 us; speedup vs baseline: 3.4562x; 3.4562x over previous
//
#include <hip/hip_runtime.h>
#include <cstdint>

#define A_N 50000
#define E_N 1200000
#define T_N 2000000
#define G_N 500
#define U_N 64
#define RBF_N 48
#define NB 3

__device__ __forceinline__ float sigf(float x){ return 1.0f/(1.0f+__expf(-x)); }
__device__ __forceinline__ float siluf(float x){ return x/(1.0f+__expf(-x)); }

// LDS bond tile layout: transposed + XOR swizzle. k = feature (0..63), e = edge-in-wave.
// Conflict-free for fixed-k-across-lanes AND fixed-e-across-lanes access patterns.
__device__ __forceinline__ int sw(int k, int e){ return k*64 + (e ^ (k & 31)); }

// atom = emb[atom_types]   (A x 64)
__global__ void k_atom_init(const int* __restrict__ types, const float* __restrict__ emb,
                            float* __restrict__ atom){
  int idx = blockIdx.x*256 + threadIdx.x;
  int a = idx >> 6, u = idx & 63;
  atom[idx] = emb[types[a]*U_N + u];
}

// bond = silu(rbf @ bW + bb)   (E x 64)
__global__ void k_bond_init(const float* __restrict__ rbf, const float* __restrict__ bW,
                            const float* __restrict__ bb, float* __restrict__ bond){
  int idx = blockIdx.x*256 + threadIdx.x;
  int e = idx >> 6, u = idx & 63;
  float acc = bb[u];
  acc += rbf[e*3+0]*bW[0*U_N+u];
  acc += rbf[e*3+1]*bW[1*U_N+u];
  acc += rbf[e*3+2]*bW[2*U_N+u];
  bond[idx] = siluf(acc);
}

// end_atom[t] = dst[tb1[t]]
__global__ void k_end(const int* __restrict__ tbi, const int* __restrict__ bai,
                      int* __restrict__ end_atom){
  int t = blockIdx.x*256 + threadIdx.x;
  if (t < T_N) end_atom[t] = bai[2*tbi[2*t+1]+1];
}

// tuo = sigmoid(atom @ tuW + tub)   (A x 48)
__global__ void k_tu(const float* __restrict__ atom, const float* __restrict__ tuW,
                     const float* __restrict__ tub, float* __restrict__ tuo){
  int idx = blockIdx.x*256 + threadIdx.x;
  int a = idx / 48, r = idx - a*48;
  const float* ar = atom + a*U_N;
  float acc = tub[r];
  #pragma unroll
  for (int v=0; v<U_N; ++v) acc += ar[v]*tuW[v*48+r];
  tuo[idx] = sigf(acc);
}

// agg[tb0] += three_basis * tuo[end_atom]
__global__ void k_triple(const float* __restrict__ tb, const int* __restrict__ tbi,
                         const int* __restrict__ end_atom, const float* __restrict__ tuo,
                         float* __restrict__ agg){
  int idx = blockIdx.x*256 + threadIdx.x;
  int t = idx / 48, r = idx - t*48;
  int b0 = tbi[2*t];
  float w = tuo[end_atom[t]*48 + r];
  atomicAdd(&agg[b0*48 + r], tb[idx]*w);
}

// accumulate an 8-wide K chunk into 32 outputs (x2 matrices). c stays in VGPRs
// (k fully unrolled); weight addresses are wave-uniform -> scalar loads broadcast
// one dword to all 64 lane-FMAs.
__device__ __forceinline__ void accum8(const float* __restrict__ W1, const float* __restrict__ W2,
                                       int kb, int ub, const float (&c)[8],
                                       float (&acc1)[32], float (&acc2)[32]){
  #pragma unroll
  for (int k=0;k<8;++k){
    const float cv = c[k];
    const float* w1 = W1 + (size_t)(kb+k)*64 + ub;
    const float* w2 = W2 + (size_t)(kb+k)*64 + ub;
    #pragma unroll
    for (int u=0;u<32;++u){
      acc1[u] = fmaf(cv, w1[u], acc1[u]);
      acc2[u] = fmaf(cv, w2[u], acc2[u]);
    }
  }
}

// Fused per-edge: bond += tf(agg); bond += gb(cat); msg = ga(bond); atom_next += msg
// 128 threads = 2 independent waves; each wave owns 64 edges (lane = edge).
// Bond tile lives in a per-wave swizzled LDS slice; weights stream via scalar loads.
__global__ __launch_bounds__(128) void k_edge(
    const float* __restrict__ agg, float* __restrict__ bond,
    const float* __restrict__ atomc, float* __restrict__ atomn,
    const int* __restrict__ bai,
    const float* __restrict__ tfW1, const float* __restrict__ tfb1,
    const float* __restrict__ tfW2, const float* __restrict__ tfb2,
    const float* __restrict__ gbW1, const float* __restrict__ gbb1,
    const float* __restrict__ gbW2, const float* __restrict__ gbb2,
    const float* __restrict__ gaW1, const float* __restrict__ gab1,
    const float* __restrict__ gaW2, const float* __restrict__ gab2)
{
  __shared__ float s_all[2*64*64];
  const int lane  = threadIdx.x & 63;
  const int w     = threadIdx.x >> 6;
  float* sb = s_all + w*4096;
  const int ebase = blockIdx.x*128 + w*64;
  const int e     = ebase + lane;

  // stage bond tile: coalesced 256B row reads, swizzled transposed LDS writes
  #pragma unroll 1
  for (int i=0;i<64;++i)
    sb[sw(lane, i)] = bond[(size_t)(ebase+i)*64 + lane];

  const float* aggr = agg + (size_t)e*48;

  // ---- phase 1: tf ----
  #pragma unroll 1
  for (int ug=0; ug<2; ++ug){
    const int ub = ug*32;
    float acc1[32], acc2[32];
    #pragma unroll
    for (int u=0;u<32;++u){ acc1[u] = tfb1[ub+u]; acc2[u] = tfb2[ub+u]; }
    #pragma unroll 1
    for (int kc=0;kc<6;++kc){
      float c[8];
      const float4* p = (const float4*)(aggr + kc*8);
      float4 v0 = p[0], v1 = p[1];
      c[0]=v0.x;c[1]=v0.y;c[2]=v0.z;c[3]=v0.w;c[4]=v1.x;c[5]=v1.y;c[6]=v1.z;c[7]=v1.w;
      accum8(tfW1, tfW2, kc*8, ub, c, acc1, acc2);
    }
    #pragma unroll
    for (int u=0;u<32;++u)
      sb[sw(ub+u, lane)] += siluf(acc1[u])*sigf(acc2[u]);
  }

  // ---- phase 2: gb (cat = [atom[src], atom[dst], bond_new]) ----
  const int src = bai[2*e], dst = bai[2*e+1];
  const float* srow = atomc + (size_t)src*64;
  const float* drow = atomc + (size_t)dst*64;
  float res0[32];                       // ug0 results stashed so ug1 still sees old bond in LDS
  #pragma unroll
  for (int ug=0; ug<2; ++ug){
    const int ub = ug*32;
    float acc1[32], acc2[32];
    #pragma unroll
    for (int u=0;u<32;++u){ acc1[u] = gbb1[ub+u]; acc2[u] = gbb2[ub+u]; }
    // segments 0,1: gathered atom rows (k 0..63 and 64..127)
    #pragma unroll 1
    for (int s=0;s<2;++s){
      const float* row = s ? drow : srow;
      const int kb = s*64;
      #pragma unroll 1
      for (int kc=0;kc<8;++kc){
        float c[8];
        const float4* p = (const float4*)(row + kc*8);
        float4 v0 = p[0], v1 = p[1];
        c[0]=v0.x;c[1]=v0.y;c[2]=v0.z;c[3]=v0.w;c[4]=v1.x;c[5]=v1.y;c[6]=v1.z;c[7]=v1.w;
        accum8(gbW1, gbW2, kb+kc*8, ub, c, acc1, acc2);
      }
    }
    // segment 2: bond_new from LDS (k 128..191)
    #pragma unroll 1
    for (int kc=0;kc<8;++kc){
      float c[8];
      #pragma unroll
      for (int j=0;j<8;++j) c[j] = sb[sw(kc*8+j, lane)];
      accum8(gbW1, gbW2, 128+kc*8, ub, c, acc1, acc2);
    }
    if (ug==0){
      #pragma unroll
      for (int u=0;u<32;++u)
        res0[u] = sb[sw(u, lane)] + siluf(acc1[u])*sigf(acc2[u]);
    } else {
      #pragma unroll
      for (int u=0;u<32;++u)
        sb[sw(32+u, lane)] += siluf(acc1[u])*sigf(acc2[u]);
      #pragma unroll
      for (int u=0;u<32;++u)
        sb[sw(u, lane)] = res0[u];
    }
  }

  // ---- phase 3: ga -> msg -> atomic accumulate into atom_next ----
  float* arow = atomn + (size_t)dst*64;
  #pragma unroll 1
  for (int ug=0; ug<2; ++ug){
    const int ub = ug*32;
    float acc1[32], acc2[32];
    #pragma unroll
    for (int u=0;u<32;++u){ acc1[u] = gab1[ub+u]; acc2[u] = gab2[ub+u]; }
    #pragma unroll 1
    for (int kc=0;kc<8;++kc){
      float c[8];
      #pragma unroll
      for (int j=0;j<8;++j) c[j] = sb[sw(kc*8+j, lane)];
      accum8(gaW1, gaW2, kc*8, ub, c, acc1, acc2);
    }
    #pragma unroll
    for (int u=0;u<32;++u)
      atomicAdd(arow + ub + u, siluf(acc1[u])*sigf(acc2[u]));
  }

  // final bond store: coalesced
  #pragma unroll 1
  for (int i=0;i<64;++i)
    bond[(size_t)(ebase+i)*64 + lane] = sb[sw(lane, i)];
}

// gate = sig(atom @ wrW + wrb); num[b] += gate*atom; cnt[b] += 1
__global__ void k_gate(const float* __restrict__ atom, const int* __restrict__ batch,
                       const float* __restrict__ wrW, const float* __restrict__ wrb,
                       float* __restrict__ num, float* __restrict__ cnt){
  int idx = blockIdx.x*256 + threadIdx.x;
  int a = idx >> 6, u = idx & 63;
  const float* ar = atom + (size_t)a*64;
  float acc = wrb[u];
  #pragma unroll
  for (int v=0;v<64;++v) acc += ar[v]*wrW[v*64+u];
  float g = sigf(acc);
  int b = batch[a];
  atomicAdd(&num[b*64+u], g*ar[u]);
  if (u==0) atomicAdd(&cnt[b], 1.0f);
}

// out[g] = silu(vec @ fW1 + fb1) @ fW2 + fb2,  vec = num/max(cnt,1)
__global__ __launch_bounds__(64) void k_final(const float* __restrict__ num, const float* __restrict__ cnt,
                        const float* __restrict__ fW1, const float* __restrict__ fb1,
                        const float* __restrict__ fW2, const float* __restrict__ fb2,
                        float* __restrict__ out){
  int g = blockIdx.x; int u = threadIdx.x;
  float inv = 1.0f / fmaxf(cnt[g], 1.0f);
  float acc = fb1[u];
  #pragma unroll
  for (int v=0;v<64;++v) acc += num[g*64+v]*inv*fW1[v*64+u];
  float p = siluf(acc)*fW2[u];
  #pragma unroll
  for (int off=32; off>0; off>>=1) p += __shfl_down(p, off, 64);
  if (u==0) out[g] = p + fb2[0];
}

extern "C" void kernel_launch(void* const* d_in, const int* in_sizes, int n_in,
                              void* d_out, int out_size, void* d_ws, size_t ws_size,
                              hipStream_t stream){
  const int*   atom_types = (const int*)d_in[0];
  const int*   bai   = (const int*)d_in[1];
  const int*   tbi   = (const int*)d_in[2];
  const int*   batch = (const int*)d_in[3];
  const float* rbf   = (const float*)d_in[4];
  const float* tb    = (const float*)d_in[5];
  const float* emb   = (const float*)d_in[6];
  const float* bW    = (const float*)d_in[7];
  const float* bb    = (const float*)d_in[8];
  const float* tuW   = (const float*)d_in[9];
  const float* tub   = (const float*)d_in[10];
  const float* tfW1  = (const float*)d_in[11];
  const float* tfb1  = (const float*)d_in[12];
  const float* tfW2  = (const float*)d_in[13];
  const float* tfb2  = (const float*)d_in[14];
  const float* gbW1  = (const float*)d_in[15];
  const float* gbb1  = (const float*)d_in[16];
  const float* gbW2  = (const float*)d_in[17];
  const float* gbb2  = (const float*)d_in[18];
  const float* gaW1  = (const float*)d_in[19];
  const float* gab1  = (const float*)d_in[20];
  const float* gaW2  = (const float*)d_in[21];
  const float* gab2  = (const float*)d_in[22];
  const float* wrW   = (const float*)d_in[23];
  const float* wrb   = (const float*)d_in[24];
  const float* fW1   = (const float*)d_in[25];
  const float* fb1   = (const float*)d_in[26];
  const float* fW2   = (const float*)d_in[27];
  const float* fb2   = (const float*)d_in[28];

  char* ws = (char*)d_ws;
  size_t off = 0;
  auto alloc = [&](size_t bytes)->char* {
    char* p = ws + off; off += (bytes + 255) & ~size_t(255); return p;
  };
  float* bond    = (float*)alloc((size_t)E_N*64*4);
  float* agg     = (float*)alloc((size_t)E_N*48*4);
  float* atomA   = (float*)alloc((size_t)A_N*64*4);
  float* atomB   = (float*)alloc((size_t)A_N*64*4);
  float* tuo     = (float*)alloc((size_t)A_N*48*4);
  int*   end_atom= (int*)  alloc((size_t)T_N*4);
  float* num     = (float*)alloc((size_t)G_N*64*4);
  float* cnt     = (float*)alloc((size_t)G_N*4);

  k_atom_init<<<A_N*64/256, 256, 0, stream>>>(atom_types, emb, atomA);
  k_bond_init<<<E_N*64/256, 256, 0, stream>>>(rbf, bW, bb, bond);
  k_end<<<(T_N+255)/256, 256, 0, stream>>>(tbi, bai, end_atom);
  hipMemsetAsync(num, 0, G_N*64*4, stream);
  hipMemsetAsync(cnt, 0, G_N*4, stream);

  float* cur = atomA; float* nxt = atomB;
  for (int i=0;i<NB;++i){
    k_tu<<<A_N*48/256, 256, 0, stream>>>(cur, tuW + (size_t)i*64*48, tub + (size_t)i*48, tuo);
    hipMemsetAsync(agg, 0, (size_t)E_N*48*4, stream);
    k_triple<<<T_N*48/256, 256, 0, stream>>>(tb, tbi, end_atom, tuo, agg);
    hipMemcpyAsync(nxt, cur, (size_t)A_N*64*4, hipMemcpyDeviceToDevice, stream);
    k_edge<<<E_N/128, 128, 0, stream>>>(agg, bond, cur, nxt, bai,
        tfW1 + (size_t)i*48*64, tfb1 + (size_t)i*64,
        tfW2 + (size_t)i*48*64, tfb2 + (size_t)i*64,
        gbW1 + (size_t)i*192*64, gbb1 + (size_t)i*64,
        gbW2 + (size_t)i*192*64, gbb2 + (size_t)i*64,
        gaW1 + (size_t)i*64*64, gab1 + (size_t)i*64,
        gaW2 + (size_t)i*64*64, gab2 + (size_t)i*64);
    float* t2 = cur; cur = nxt; nxt = t2;
  }
  k_gate<<<A_N*64/256, 256, 0, stream>>>(cur, batch, wrW, wrb, num, cnt);
  k_final<<<G_N, 64, 0, stream>>>(num, cnt, fW1, fb1, fW2, fb2, (float*)d_out);
}